// Round 5
// baseline (994.132 us; speedup 1.0000x reference)
//
#include <hip/hip_runtime.h>
#include <math.h>

// Problem constants
#define BB 16
#define TT 2048
#define DD 512
#define WW 12
#define TQ 512
#define NROWS (BB * TQ)

typedef _Float16 f16;
typedef __attribute__((ext_vector_type(8))) _Float16 f16x8;
typedef __attribute__((ext_vector_type(4))) _Float16 f16x4;
typedef __attribute__((ext_vector_type(4))) float f32x4;

#define MFMA16(a, b, c) __builtin_amdgcn_mfma_f32_16x16x32_f16((a), (b), (c), 0, 0, 0)

// ws layout
#define WS_IDS  0u
#define WS_W16  (512u * 1024u)              // 3072 x 512 f16 = 3 MB ([w_ih ; w_hh])
#define WS_H16  (4u * 1024u * 1024u)        // 8192 x 512 f16 = 8 MB (ping)

__device__ __forceinline__ float fsigm(float v) { return 1.0f / (1.0f + __expf(-v)); }
__device__ __forceinline__ float ftanh(float v) {
    float a = fabsf(v);
    float t = __expf(-2.0f * a);
    float r = (1.0f - t) / (1.0f + t);
    return copysignf(r, v);
}

__device__ __forceinline__ f16x8 cvt8(float4 a, float4 b) {
    f16x8 r;
    r[0] = (_Float16)a.x; r[1] = (_Float16)a.y; r[2] = (_Float16)a.z; r[3] = (_Float16)a.w;
    r[4] = (_Float16)b.x; r[5] = (_Float16)b.y; r[6] = (_Float16)b.z; r[7] = (_Float16)b.w;
    return r;
}

// -------- Kernel 1: band top-k selection, coalesced candidate streams -------
// 256 thr = 4 waves = 4 queries. lane = (i, c): c = lane&3 candidate stream,
// i = lane>>2 k-slice (16 lanes x 16B = 256B contiguous per row per load).
// 6 rounds x 4 candidates cover <=23. fp64 accumulate (exact vs fp32 ranking).
__global__ __launch_bounds__(256) void select_topk_kernel(
    const float* __restrict__ x, int* __restrict__ ids)
{
    const int tid = threadIdx.x, wid = tid >> 6, lane = tid & 63;
    const int bid = blockIdx.x;                    // 0..2047
    const int swz = (bid & 7) * 256 + (bid >> 3);  // XCD-chunked
    const int n = swz * 4 + wid;
    const int b = n >> 9, qi = n & 511;

    int t = (qi == TQ - 1) ? (TT - 1)
          : (int)((double)qi * ((double)(TT - 1) / (double)(TQ - 1)));
    int j0 = t - (WW - 1); if (j0 < 0) j0 = 0;
    int j1 = t + (WW - 1); if (j1 > TT - 1) j1 = TT - 1;
    const int ncand = j1 - j0 + 1;                 // 12..23

    const int c = lane & 3, i = lane >> 2;
    const float* qrow = x + ((size_t)b * TT + t) * DD + i * 4;

    // hoist q into registers (8 x float4, stride 64 f32)
    float4 q[8];
#pragma unroll
    for (int it = 0; it < 8; ++it) q[it] = *(const float4*)(qrow + it * 64);

    double s[6];
#pragma unroll
    for (int r = 0; r < 6; ++r) {
        int cc = r * 4 + c;
        double s0 = 0.0, s1 = 0.0;
        if (cc < ncand) {
            const float* krow = x + ((size_t)b * TT + (j0 + cc)) * DD + i * 4;
#pragma unroll
            for (int it = 0; it < 8; ++it) {
                float4 kv = *(const float4*)(krow + it * 64);
                s0 = fma((double)q[it].x, (double)kv.x, s0);
                s1 = fma((double)q[it].y, (double)kv.y, s1);
                s0 = fma((double)q[it].z, (double)kv.z, s0);
                s1 = fma((double)q[it].w, (double)kv.w, s1);
            }
        }
        double sv = s0 + s1;
        sv += __shfl_xor(sv, 4);
        sv += __shfl_xor(sv, 8);
        sv += __shfl_xor(sv, 16);
        sv += __shfl_xor(sv, 32);
        s[r] = sv;                                 // candidate r*4 + c, all i-lanes
    }

    // lane j holds candidate j's score in s[j>>2] (since j&3 == c)
    const int rr = lane >> 2;
    double sj = s[0];
    sj = (rr == 1) ? s[1] : sj;
    sj = (rr == 2) ? s[2] : sj;
    sj = (rr == 3) ? s[3] : sj;
    sj = (rr == 4) ? s[4] : sj;
    sj = (rr == 5) ? s[5] : sj;
    bool valid = lane < ncand;
    if (!valid) sj = -1.0e300;

    int rank = 0;
    for (int kk = 0; kk < 2 * WW - 1; ++kk) {
        if (kk >= ncand) break;                    // wave-uniform
        double bs = __shfl(sj, kk);
        rank += (bs > sj || (bs == sj && kk < lane)) ? 1 : 0;
    }
    bool sel = valid && (rank < WW);
    unsigned long long m = __ballot(sel);
    if (sel) {
        int pos = __popcll(m & ((1ull << lane) - 1ull));
        ids[(size_t)n * WW + pos] = j0 + lane;
    }
}

// -------- Kernel 2: f32 -> f16 weight conversion ---------------------------
__global__ __launch_bounds__(256) void convert_w_kernel(
    const float* __restrict__ wi, const float* __restrict__ wh, f16* __restrict__ w16)
{
    const int PER = 3 * DD * DD / 4;
    int i = blockIdx.x * 256 + threadIdx.x;
    float4 v;
    if (i < PER) v = ((const float4*)wi)[i];
    else         v = ((const float4*)wh)[i - PER];
    f16x4 o;
    o[0] = (_Float16)v.x; o[1] = (_Float16)v.y; o[2] = (_Float16)v.z; o[3] = (_Float16)v.w;
    *(f16x4*)(w16 + (size_t)i * 4) = o;
}

// -------- Kernel 3: fused GRU step, f16 MFMA, 2 blocks/CU ------------------
// Grid 512 = 64 rb x 8 cb; XCD = bid&7 owns rb in [8*xcd, 8*xcd+8) x all cb.
// Block 256 thr / 4 waves (wm 0..1, wn 0..1); wave tile 64 rows x 32 cols.
// LDS 65 KB -> 2 blocks/CU. B: 2x24KB gload_lds (round-4 proven swizzle);
// x: reg-staged f32->f16 into 2x8KB; h: prefetched per-lane global uint4.
template<bool HAS_H>
__global__ __launch_bounds__(256, 2) void gru_step_kernel(
    const float* __restrict__ x,
    const int* __restrict__ ids,
    const f16* __restrict__ w16,        // [3072][512]
    const float* __restrict__ b_ih,
    const float* __restrict__ b_hh,
    const f16* __restrict__ h16r,
    f16* __restrict__ h16w,
    float* __restrict__ f32w,
    int step)
{
    __shared__ __align__(16) char sB[2][24 * 1024];
    __shared__ __align__(16) char sX[2][8 * 1024];
    __shared__ int sXrow[128];

    const int tid = threadIdx.x;
    const int lane = tid & 63, wid = tid >> 6;
    const int wm = wid >> 1, wn = wid & 1;
    const int l15 = lane & 15, lhi = lane >> 4;
    const int bid = blockIdx.x;
    const int xcd = bid & 7, idx = bid >> 3;
    const int rb = xcd * 8 + (idx & 7);
    const int cb = idx >> 3;
    const int row0 = rb * 128, c0 = cb * 64;

    if (tid < 128) {
        int nn = row0 + tid;
        sXrow[tid] = (nn >> 9) * TT + ids[(size_t)nn * WW + step];
    }
    __syncthreads();

    // ---- B staging: 6 chunks/wave (24 total; chunk = 1KB = 16 cols x 4 slots)
    const f16* bsrc[6]; int bdst[6]; bool bact[6];
    {
        const int slot = lane & 3, lc = lane >> 2;
#pragma unroll
        for (int ii = 0; ii < 6; ++ii) {
            int ch = wid * 6 + ii;
            int g = ch >> 2, cg = ch & 3;
            int col = cg * 16 + lc;
            bact[ii] = HAS_H || (g < 3);
            bsrc[ii] = w16 + ((size_t)(g * 512 + c0 + col) * 512
                              + (size_t)((slot ^ ((col >> 1) & 3)) * 8));
            bdst[ii] = ch * 1024;
        }
    }
    // ---- x staging (reg path): 2 lanes/row; lane covers slots {2b, 2b+1}
    const int myrow = tid >> 1;                       // 0..127
    const int bsel = tid & 1;
    const int cA = (2 * bsel) ^ ((myrow >> 1) & 3);
    const float* xsrc = x + (size_t)sXrow[myrow] * DD;
    const float* xp0 = xsrc + cA * 8;
    const float* xp1 = xsrc + (cA ^ 1) * 8;
    const int xw0 = myrow * 64 + (2 * bsel) * 16;     // LDS byte offset

    // ---- h prefetch pointers (per-lane global)
    const char* hp[4];
    if (HAS_H) {
#pragma unroll
        for (int mf = 0; mf < 4; ++mf) {
            int rl = wm * 64 + mf * 16 + l15;
            hp[mf] = (const char*)(h16r + (size_t)(row0 + rl) * DD + lhi * 8);
        }
    }

    // ---- fragment read offsets (shared swizzle term)
    const int swzo = (lhi ^ ((l15 >> 1) & 3)) * 16;
    const int aA0 = (wm * 64 + l15) * 64 + swzo;            // + mf*1024
    int colb[2];
#pragma unroll
    for (int nf = 0; nf < 2; ++nf)
        colb[nf] = (wn * 32 + nf * 16 + l15) * 64 + swzo;   // + g*4096

    f32x4 accR[4][2], accZ[4][2], accIN[4][2], accHN[4][2];
#pragma unroll
    for (int mf = 0; mf < 4; ++mf)
#pragma unroll
        for (int nf = 0; nf < 2; ++nf) {
            f32x4 z = {0.f, 0.f, 0.f, 0.f};
            accR[mf][nf] = z; accZ[mf][nf] = z; accIN[mf][nf] = z; accHN[mf][nf] = z;
        }

    uint4 hvA[4], hvB[4];

    // ---- prologue: fill buffer 0 (k0 = 0), prefetch h(0)
    {
#pragma unroll
        for (int ii = 0; ii < 6; ++ii)
            if (bact[ii])
                __builtin_amdgcn_global_load_lds(
                    (const __attribute__((address_space(1))) unsigned*)bsrc[ii],
                    (__attribute__((address_space(3))) unsigned*)(&sB[0][0] + bdst[ii]), 16, 0, 0);
        float4 a0 = *(const float4*)(xp0);
        float4 a1 = *(const float4*)(xp0 + 4);
        float4 a2 = *(const float4*)(xp1);
        float4 a3 = *(const float4*)(xp1 + 4);
        if (HAS_H) {
#pragma unroll
            for (int mf = 0; mf < 4; ++mf) hvA[mf] = *(const uint4*)(hp[mf]);
        }
        *(f16x8*)(&sX[0][0] + xw0)      = cvt8(a0, a1);
        *(f16x8*)(&sX[0][0] + xw0 + 16) = cvt8(a2, a3);
    }

#define GRU_ITER(KS, CUR, HVIN, HVOUT)                                          \
    {                                                                           \
        asm volatile("s_waitcnt vmcnt(0)" ::: "memory");                        \
        __syncthreads();                                                        \
        const int kn = ((KS) + 1) * 32;                                         \
        float4 a0, a1, a2, a3;                                                  \
        if ((KS) < 15) {                                                        \
            _Pragma("unroll")                                                   \
            for (int ii = 0; ii < 6; ++ii)                                      \
                if (bact[ii])                                                   \
                    __builtin_amdgcn_global_load_lds(                           \
                        (const __attribute__((address_space(1))) unsigned*)(bsrc[ii] + kn), \
                        (__attribute__((address_space(3))) unsigned*)(&sB[(CUR) ^ 1][0] + bdst[ii]), 16, 0, 0); \
            a0 = *(const float4*)(xp0 + kn);                                    \
            a1 = *(const float4*)(xp0 + kn + 4);                                \
            a2 = *(const float4*)(xp1 + kn);                                    \
            a3 = *(const float4*)(xp1 + kn + 4);                                \
            if (HAS_H) {                                                        \
                _Pragma("unroll")                                               \
                for (int mf = 0; mf < 4; ++mf)                                  \
                    HVOUT[mf] = *(const uint4*)(hp[mf] + kn * 2);               \
            }                                                                   \
        }                                                                       \
        f16x8 ax[4], ah[4];                                                     \
        _Pragma("unroll")                                                       \
        for (int mf = 0; mf < 4; ++mf) {                                        \
            ax[mf] = *(const f16x8*)(&sX[CUR][0] + aA0 + mf * 1024);            \
            if (HAS_H) ah[mf] = *(const f16x8*)&HVIN[mf];                       \
        }                                                                       \
        __builtin_amdgcn_s_setprio(1);                                          \
        _Pragma("unroll")                                                       \
        for (int nf = 0; nf < 2; ++nf) {                                        \
            const char* bb = &sB[CUR][0] + colb[nf];                            \
            f16x8 B0 = *(const f16x8*)(bb + 0 * 4096);                          \
            f16x8 B1 = *(const f16x8*)(bb + 1 * 4096);                          \
            f16x8 B2 = *(const f16x8*)(bb + 2 * 4096);                          \
            f16x8 B3, B4, B5;                                                   \
            if (HAS_H) {                                                        \
                B3 = *(const f16x8*)(bb + 3 * 4096);                            \
                B4 = *(const f16x8*)(bb + 4 * 4096);                            \
                B5 = *(const f16x8*)(bb + 5 * 4096);                            \
            }                                                                   \
            _Pragma("unroll")                                                   \
            for (int mf = 0; mf < 4; ++mf) {                                    \
                accR[mf][nf]  = MFMA16(ax[mf], B0, accR[mf][nf]);               \
                accZ[mf][nf]  = MFMA16(ax[mf], B1, accZ[mf][nf]);               \
                accIN[mf][nf] = MFMA16(ax[mf], B2, accIN[mf][nf]);              \
                if (HAS_H) {                                                    \
                    accR[mf][nf]  = MFMA16(ah[mf], B3, accR[mf][nf]);           \
                    accZ[mf][nf]  = MFMA16(ah[mf], B4, accZ[mf][nf]);           \
                    accHN[mf][nf] = MFMA16(ah[mf], B5, accHN[mf][nf]);          \
                }                                                               \
            }                                                                   \
        }                                                                       \
        __builtin_amdgcn_s_setprio(0);                                          \
        if ((KS) < 15) {                                                        \
            *(f16x8*)(&sX[(CUR) ^ 1][0] + xw0)      = cvt8(a0, a1);             \
            *(f16x8*)(&sX[(CUR) ^ 1][0] + xw0 + 16) = cvt8(a2, a3);             \
        }                                                                       \
    }

    for (int ks2 = 0; ks2 < 16; ks2 += 2) {
        GRU_ITER(ks2, 0, hvA, hvB);
        GRU_ITER(ks2 + 1, 1, hvB, hvA);
    }
#undef GRU_ITER

    // ---- epilogue
#pragma unroll
    for (int nf = 0; nf < 2; ++nf) {
        int col = c0 + wn * 32 + nf * 16 + l15;
        float bir = b_ih[col],          bhr = b_hh[col];
        float biz = b_ih[DD + col],     bhz = b_hh[DD + col];
        float bin = b_ih[2 * DD + col], bhn = b_hh[2 * DD + col];
#pragma unroll
        for (int mf = 0; mf < 4; ++mf) {
#pragma unroll
            for (int r = 0; r < 4; ++r) {
                int row = row0 + wm * 64 + mf * 16 + lhi * 4 + r;
                size_t off = (size_t)row * DD + col;
                float hold = HAS_H ? (float)h16r[off] : 0.0f;
                float R = fsigm(accR[mf][nf][r] + bir + bhr);
                float Z = fsigm(accZ[mf][nf][r] + biz + bhz);
                float Nn = ftanh(accIN[mf][nf][r] + bin + R * (accHN[mf][nf][r] + bhn));
                float res = (1.0f - Z) * Nn + Z * hold;
                if (h16w) h16w[off] = (f16)res;
                if (f32w) f32w[off] = res;
            }
        }
    }
}

// ---------------------------------------------------------------------------
extern "C" void kernel_launch(void* const* d_in, const int* in_sizes, int n_in,
                              void* d_out, int out_size, void* d_ws, size_t ws_size,
                              hipStream_t stream)
{
    const float* x    = (const float*)d_in[0];
    const float* w_ih = (const float*)d_in[1];
    const float* w_hh = (const float*)d_in[2];
    const float* b_ih = (const float*)d_in[3];
    const float* b_hh = (const float*)d_in[4];

    char* ws = (char*)d_ws;
    int*  ids = (int*)(ws + WS_IDS);
    f16*  w16 = (f16*)(ws + WS_W16);
    f16*  P0  = (f16*)(ws + WS_H16);       // ping
    f16*  P1  = (f16*)d_out;               // pong (aliases d_out; last step writes f32)

    select_topk_kernel<<<dim3(NROWS / 4), dim3(256), 0, stream>>>(x, ids);
    convert_w_kernel<<<dim3(1536), dim3(256), 0, stream>>>(w_ih, w_hh, w16);

    for (int s = 0; s < WW; ++s) {
        const f16* hr = (s == 0) ? nullptr : ((s & 1) ? P0 : P1);
        f16* hw      = (s == WW - 1) ? nullptr : ((s & 1) ? P1 : P0);
        float* fo    = (s == WW - 1) ? (float*)d_out : nullptr;
        if (s == 0)
            gru_step_kernel<false><<<dim3(512), dim3(256), 0, stream>>>(
                x, ids, w16, b_ih, b_hh, hr, hw, fo, s);
        else
            gru_step_kernel<true><<<dim3(512), dim3(256), 0, stream>>>(
                x, ids, w16, b_ih, b_hh, hr, hw, fo, s);
    }
}

// Round 6
// 555.896 us; speedup vs baseline: 1.7883x; 1.7883x over previous
//
#include <hip/hip_runtime.h>
#include <math.h>

// Problem constants
#define BB 16
#define TT 2048
#define DD 512
#define WW 12
#define TQ 512
#define NROWS (BB * TQ)

typedef _Float16 f16;
typedef __attribute__((ext_vector_type(8))) _Float16 f16x8;
typedef __attribute__((ext_vector_type(4))) _Float16 f16x4;
typedef __attribute__((ext_vector_type(4))) float f32x4;

#define MFMA16(a, b, c) __builtin_amdgcn_mfma_f32_16x16x32_f16((a), (b), (c), 0, 0, 0)

// ws layout
#define WS_IDS  0u
#define WS_W16  (512u * 1024u)              // 3072 x 512 f16 = 3 MB ([w_ih ; w_hh])
#define WS_H16  (4u * 1024u * 1024u)        // 8192 x 512 f16 = 8 MB (ping)
#define WS_GI   (12u * 1024u * 1024u)       // 32768 x 1536 f16 = 96 MB
#define WS_NEED (108ull * 1024ull * 1024ull)

__device__ __forceinline__ float fsigm(float v) { return 1.0f / (1.0f + __expf(-v)); }
__device__ __forceinline__ float ftanh(float v) {
    float a = fabsf(v);
    float t = __expf(-2.0f * a);
    float r = (1.0f - t) / (1.0f + t);
    return copysignf(r, v);
}

__device__ __forceinline__ f16x8 cvt8(float4 a, float4 b) {
    f16x8 r;
    r[0] = (_Float16)a.x; r[1] = (_Float16)a.y; r[2] = (_Float16)a.z; r[3] = (_Float16)a.w;
    r[4] = (_Float16)b.x; r[5] = (_Float16)b.y; r[6] = (_Float16)b.z; r[7] = (_Float16)b.w;
    return r;
}

// -------- Kernel 1: band top-k selection (round-5, coalesced streams) -------
__global__ __launch_bounds__(256) void select_topk_kernel(
    const float* __restrict__ x, int* __restrict__ ids)
{
    const int tid = threadIdx.x, wid = tid >> 6, lane = tid & 63;
    const int bid = blockIdx.x;
    const int swz = (bid & 7) * 256 + (bid >> 3);
    const int n = swz * 4 + wid;
    const int b = n >> 9, qi = n & 511;

    int t = (qi == TQ - 1) ? (TT - 1)
          : (int)((double)qi * ((double)(TT - 1) / (double)(TQ - 1)));
    int j0 = t - (WW - 1); if (j0 < 0) j0 = 0;
    int j1 = t + (WW - 1); if (j1 > TT - 1) j1 = TT - 1;
    const int ncand = j1 - j0 + 1;

    const int c = lane & 3, i = lane >> 2;
    const float* qrow = x + ((size_t)b * TT + t) * DD + i * 4;

    float4 q[8];
#pragma unroll
    for (int it = 0; it < 8; ++it) q[it] = *(const float4*)(qrow + it * 64);

    double s[6];
#pragma unroll
    for (int r = 0; r < 6; ++r) {
        int cc = r * 4 + c;
        double s0 = 0.0, s1 = 0.0;
        if (cc < ncand) {
            const float* krow = x + ((size_t)b * TT + (j0 + cc)) * DD + i * 4;
#pragma unroll
            for (int it = 0; it < 8; ++it) {
                float4 kv = *(const float4*)(krow + it * 64);
                s0 = fma((double)q[it].x, (double)kv.x, s0);
                s1 = fma((double)q[it].y, (double)kv.y, s1);
                s0 = fma((double)q[it].z, (double)kv.z, s0);
                s1 = fma((double)q[it].w, (double)kv.w, s1);
            }
        }
        double sv = s0 + s1;
        sv += __shfl_xor(sv, 4);
        sv += __shfl_xor(sv, 8);
        sv += __shfl_xor(sv, 16);
        sv += __shfl_xor(sv, 32);
        s[r] = sv;
    }

    const int rr = lane >> 2;
    double sj = s[0];
    sj = (rr == 1) ? s[1] : sj;
    sj = (rr == 2) ? s[2] : sj;
    sj = (rr == 3) ? s[3] : sj;
    sj = (rr == 4) ? s[4] : sj;
    sj = (rr == 5) ? s[5] : sj;
    bool valid = lane < ncand;
    if (!valid) sj = -1.0e300;

    int rank = 0;
    for (int kk = 0; kk < 2 * WW - 1; ++kk) {
        if (kk >= ncand) break;
        double bs = __shfl(sj, kk);
        rank += (bs > sj || (bs == sj && kk < lane)) ? 1 : 0;
    }
    bool sel = valid && (rank < WW);
    unsigned long long m = __ballot(sel);
    if (sel) {
        int pos = __popcll(m & ((1ull << lane) - 1ull));
        ids[(size_t)n * WW + pos] = j0 + lane;
    }
}

// -------- Kernel 2: f32 -> f16 weight conversion ---------------------------
__global__ __launch_bounds__(256) void convert_w_kernel(
    const float* __restrict__ wi, const float* __restrict__ wh, f16* __restrict__ w16)
{
    const int PER = 3 * DD * DD / 4;
    int i = blockIdx.x * 256 + threadIdx.x;
    float4 v;
    if (i < PER) v = ((const float4*)wi)[i];
    else         v = ((const float4*)wh)[i - PER];
    f16x4 o;
    o[0] = (_Float16)v.x; o[1] = (_Float16)v.y; o[2] = (_Float16)v.z; o[3] = (_Float16)v.w;
    *(f16x4*)(w16 + (size_t)i * 4) = o;
}

// -------- Kernel 3 (path A): GI = x @ w_ih.T + b_ih for ALL 32768 rows -----
// 256 thr / 4 waves; tile 128 rows x 64 cols; grid 6144 = 256 rb x 24 cb.
__global__ __launch_bounds__(256, 4) void gi_gemm_kernel(
    const float* __restrict__ x,
    const f16* __restrict__ w16,        // rows 0..1535 = w_ih
    const float* __restrict__ b_ih,
    f16* __restrict__ gi)               // [32768][1536]
{
    __shared__ __align__(16) char sB[2][4 * 1024];
    __shared__ __align__(16) char sX[2][8 * 1024];

    const int tid = threadIdx.x;
    const int lane = tid & 63, wid = tid >> 6;
    const int wm = wid >> 1, wn = wid & 1;
    const int l15 = lane & 15, lhi = lane >> 4;
    const int bid = blockIdx.x;
    const int xcd = bid & 7, idx = bid >> 3;          // 0..767
    const int cb = idx % 24, rb = xcd * 32 + idx / 24;
    const int row0 = rb * 128, c0 = cb * 64;

    // B staging: 1 chunk (1KB = 16 cols x 4 slots) per wave per buffer
    const int slot = lane & 3, lc = lane >> 2;
    const int colB = wid * 16 + lc;
    const f16* bsrc = w16 + ((size_t)(c0 + colB) * 512
                             + (size_t)((slot ^ ((colB >> 1) & 3)) * 8));
    const int bdst = wid * 1024;

    // x staging (reg path): 2 lanes/row
    const int myrow = tid >> 1, bsel = tid & 1;
    const int cA = (2 * bsel) ^ ((myrow >> 1) & 3);
    const float* xsrc = x + (size_t)(row0 + myrow) * DD;
    const float* xp0 = xsrc + cA * 8;
    const float* xp1 = xsrc + (cA ^ 1) * 8;
    const int xw0 = myrow * 64 + (2 * bsel) * 16;

    const int swzo = (lhi ^ ((l15 >> 1) & 3)) * 16;
    const int aA0 = (wm * 64 + l15) * 64 + swzo;
    int colb[2];
#pragma unroll
    for (int nf = 0; nf < 2; ++nf)
        colb[nf] = (wn * 32 + nf * 16 + l15) * 64 + swzo;

    f32x4 acc[4][2];
#pragma unroll
    for (int mf = 0; mf < 4; ++mf)
#pragma unroll
        for (int nf = 0; nf < 2; ++nf) { f32x4 z = {0.f,0.f,0.f,0.f}; acc[mf][nf] = z; }

    // prologue
    {
        __builtin_amdgcn_global_load_lds(
            (const __attribute__((address_space(1))) unsigned*)bsrc,
            (__attribute__((address_space(3))) unsigned*)(&sB[0][0] + bdst), 16, 0, 0);
        float4 a0 = *(const float4*)(xp0);
        float4 a1 = *(const float4*)(xp0 + 4);
        float4 a2 = *(const float4*)(xp1);
        float4 a3 = *(const float4*)(xp1 + 4);
        *(f16x8*)(&sX[0][0] + xw0)      = cvt8(a0, a1);
        *(f16x8*)(&sX[0][0] + xw0 + 16) = cvt8(a2, a3);
    }

    int cur = 0;
    for (int ks = 0; ks < 16; ++ks) {
        asm volatile("s_waitcnt vmcnt(0)" ::: "memory");
        __syncthreads();

        float4 a0, a1, a2, a3;
        const int kn = (ks + 1) * 32;
        if (ks < 15) {
            __builtin_amdgcn_global_load_lds(
                (const __attribute__((address_space(1))) unsigned*)(bsrc + kn),
                (__attribute__((address_space(3))) unsigned*)(&sB[cur ^ 1][0] + bdst), 16, 0, 0);
            a0 = *(const float4*)(xp0 + kn);
            a1 = *(const float4*)(xp0 + kn + 4);
            a2 = *(const float4*)(xp1 + kn);
            a3 = *(const float4*)(xp1 + kn + 4);
        }

        f16x8 ax[4];
#pragma unroll
        for (int mf = 0; mf < 4; ++mf)
            ax[mf] = *(const f16x8*)(&sX[cur][0] + aA0 + mf * 1024);

#pragma unroll
        for (int nf = 0; nf < 2; ++nf) {
            f16x8 Bv = *(const f16x8*)(&sB[cur][0] + colb[nf]);
#pragma unroll
            for (int mf = 0; mf < 4; ++mf)
                acc[mf][nf] = MFMA16(ax[mf], Bv, acc[mf][nf]);
        }

        if (ks < 15) {
            *(f16x8*)(&sX[cur ^ 1][0] + xw0)      = cvt8(a0, a1);
            *(f16x8*)(&sX[cur ^ 1][0] + xw0 + 16) = cvt8(a2, a3);
        }
        cur ^= 1;
    }

#pragma unroll
    for (int nf = 0; nf < 2; ++nf) {
        int col = c0 + wn * 32 + nf * 16 + l15;
        float bi = b_ih[col];
#pragma unroll
        for (int mf = 0; mf < 4; ++mf)
#pragma unroll
            for (int r = 0; r < 4; ++r) {
                int row = row0 + wm * 64 + mf * 16 + lhi * 4 + r;
                gi[(size_t)row * 1536 + col] = (f16)(acc[mf][nf][r] + bi);
            }
    }
}

// -------- Kernel 4 (path A): step 0 elementwise (h0 = 0) -------------------
__global__ __launch_bounds__(256) void step0_kernel(
    const int* __restrict__ ids, const f16* __restrict__ gi,
    const float* __restrict__ b_hh, f16* __restrict__ h16w)
{
    int g = blockIdx.x * 256 + threadIdx.x;        // 0 .. 8192*64-1
    int row = g >> 6;
    int c8 = (g & 63) * 8;
    int src = (row >> 9) * TT + ids[(size_t)row * WW + 0];
    const f16* gr = gi + (size_t)src * 1536 + c8;
    f16x8 vr = *(const f16x8*)(gr);
    f16x8 vz = *(const f16x8*)(gr + 512);
    f16x8 vn = *(const f16x8*)(gr + 1024);
    f16x8 out;
#pragma unroll
    for (int j = 0; j < 8; ++j) {
        int col = c8 + j;
        float R = fsigm((float)vr[j] + b_hh[col]);
        float Z = fsigm((float)vz[j] + b_hh[DD + col]);
        float N = ftanh((float)vn[j] + R * b_hh[2 * DD + col]);
        out[j] = (f16)((1.0f - Z) * N);
    }
    *(f16x8*)(h16w + (size_t)row * DD + c8) = out;
}

// -------- Kernel 5 (path A): h-side-only GRU step --------------------------
// 256 thr / 4 waves; tile 128 rows x 64 cols; LDS 41 KB -> 2 blocks/CU.
// B = 3 w_hh gates staged 2x12KB; h staged 2x8KB; GI gathered in epilogue.
__global__ __launch_bounds__(256, 2) void gru_step_h_kernel(
    const int* __restrict__ ids,
    const f16* __restrict__ w16,        // rows 1536..3071 = w_hh
    const float* __restrict__ b_hh,
    const f16* __restrict__ gi,
    const f16* __restrict__ h16r,
    f16* __restrict__ h16w,
    float* __restrict__ f32w,
    int step)
{
    __shared__ __align__(16) char sB[2][12 * 1024];
    __shared__ __align__(16) char sH[2][8 * 1024];
    __shared__ int sXrow[128];

    const int tid = threadIdx.x;
    const int lane = tid & 63, wid = tid >> 6;
    const int wm = wid >> 1, wn = wid & 1;
    const int l15 = lane & 15, lhi = lane >> 4;
    const int bid = blockIdx.x;
    const int xcd = bid & 7, idx = bid >> 3;       // 0..63
    const int rb = xcd * 8 + (idx & 7);
    const int cb = idx >> 3;
    const int row0 = rb * 128, c0 = cb * 64;

    if (tid < 128) {
        int nn = row0 + tid;
        sXrow[tid] = (nn >> 9) * TT + ids[(size_t)nn * WW + step];
    }

    // B staging: 3 chunks/wave (12 total; 1KB = 16 cols x 4 slots)
    const int slot = lane & 3, lc = lane >> 2;
    const f16* bsrc[3]; int bdst[3];
#pragma unroll
    for (int ii = 0; ii < 3; ++ii) {
        int ch = wid * 3 + ii;
        int gg = ch >> 2, cg = ch & 3;
        int col = cg * 16 + lc;
        bsrc[ii] = w16 + ((size_t)(1536 + gg * 512 + c0 + col) * 512
                          + (size_t)((slot ^ ((col >> 1) & 3)) * 8));
        bdst[ii] = ch * 1024;
    }
    // h staging: 2 chunks/wave (8 total; 1KB = 16 rows x 4 slots)
    const f16* hsrc[2]; int hdst[2];
#pragma unroll
    for (int ii = 0; ii < 2; ++ii) {
        int ch = wid * 2 + ii;
        int hrow = ch * 16 + lc;
        hsrc[ii] = h16r + ((size_t)(row0 + hrow) * 512
                           + (size_t)((slot ^ ((lc >> 1) & 3)) * 8));
        hdst[ii] = ch * 1024;
    }

    const int swzo = (lhi ^ ((l15 >> 1) & 3)) * 16;
    const int aA0 = (wm * 64 + l15) * 64 + swzo;
    int colb[2];
#pragma unroll
    for (int nf = 0; nf < 2; ++nf)
        colb[nf] = (wn * 32 + nf * 16 + l15) * 64 + swzo;

    f32x4 accR[4][2], accZ[4][2], accHN[4][2];
#pragma unroll
    for (int mf = 0; mf < 4; ++mf)
#pragma unroll
        for (int nf = 0; nf < 2; ++nf) {
            f32x4 z = {0.f, 0.f, 0.f, 0.f};
            accR[mf][nf] = z; accZ[mf][nf] = z; accHN[mf][nf] = z;
        }

    // prologue: fill buffer 0
#pragma unroll
    for (int ii = 0; ii < 3; ++ii)
        __builtin_amdgcn_global_load_lds(
            (const __attribute__((address_space(1))) unsigned*)bsrc[ii],
            (__attribute__((address_space(3))) unsigned*)(&sB[0][0] + bdst[ii]), 16, 0, 0);
#pragma unroll
    for (int ii = 0; ii < 2; ++ii)
        __builtin_amdgcn_global_load_lds(
            (const __attribute__((address_space(1))) unsigned*)hsrc[ii],
            (__attribute__((address_space(3))) unsigned*)(&sH[0][0] + hdst[ii]), 16, 0, 0);

    int cur = 0;
    for (int ks = 0; ks < 16; ++ks) {
        asm volatile("s_waitcnt vmcnt(0)" ::: "memory");
        __syncthreads();

        const int kn = (ks + 1) * 32;
        if (ks < 15) {
#pragma unroll
            for (int ii = 0; ii < 3; ++ii)
                __builtin_amdgcn_global_load_lds(
                    (const __attribute__((address_space(1))) unsigned*)(bsrc[ii] + kn),
                    (__attribute__((address_space(3))) unsigned*)(&sB[cur ^ 1][0] + bdst[ii]), 16, 0, 0);
#pragma unroll
            for (int ii = 0; ii < 2; ++ii)
                __builtin_amdgcn_global_load_lds(
                    (const __attribute__((address_space(1))) unsigned*)(hsrc[ii] + kn),
                    (__attribute__((address_space(3))) unsigned*)(&sH[cur ^ 1][0] + hdst[ii]), 16, 0, 0);
        }

        f16x8 ah[4];
#pragma unroll
        for (int mf = 0; mf < 4; ++mf)
            ah[mf] = *(const f16x8*)(&sH[cur][0] + aA0 + mf * 1024);

#pragma unroll
        for (int nf = 0; nf < 2; ++nf) {
            const char* bb = &sB[cur][0] + colb[nf];
            f16x8 B0 = *(const f16x8*)(bb + 0 * 4096);
            f16x8 B1 = *(const f16x8*)(bb + 1 * 4096);
            f16x8 B2 = *(const f16x8*)(bb + 2 * 4096);
#pragma unroll
            for (int mf = 0; mf < 4; ++mf) {
                accR[mf][nf]  = MFMA16(ah[mf], B0, accR[mf][nf]);
                accZ[mf][nf]  = MFMA16(ah[mf], B1, accZ[mf][nf]);
                accHN[mf][nf] = MFMA16(ah[mf], B2, accHN[mf][nf]);
            }
        }
        cur ^= 1;
    }

    // epilogue: gather GI, gates, state update
#pragma unroll
    for (int nf = 0; nf < 2; ++nf) {
        int col = c0 + wn * 32 + nf * 16 + l15;
        float bhr = b_hh[col];
        float bhz = b_hh[DD + col];
        float bhn = b_hh[2 * DD + col];
#pragma unroll
        for (int mf = 0; mf < 4; ++mf) {
#pragma unroll
            for (int r = 0; r < 4; ++r) {
                int row = row0 + wm * 64 + mf * 16 + lhi * 4 + r;
                size_t off = (size_t)row * DD + col;
                int src = sXrow[row - row0];
                const f16* gr = gi + (size_t)src * 1536 + col;
                float gir = (float)gr[0];
                float giz = (float)gr[512];
                float gin = (float)gr[1024];
                float hold = (float)h16r[off];
                float R = fsigm(gir + accR[mf][nf][r] + bhr);
                float Z = fsigm(giz + accZ[mf][nf][r] + bhz);
                float N = ftanh(gin + R * (accHN[mf][nf][r] + bhn));
                float res = (1.0f - Z) * N + Z * hold;
                if (h16w) h16w[off] = (f16)res;
                if (f32w) f32w[off] = res;
            }
        }
    }
}

// -------- Kernel 6 (path B fallback): round-4 both-sides step --------------
template<bool HAS_H>
__global__ __launch_bounds__(512, 2) void gru_step_full_kernel(
    const float* __restrict__ x,
    const int* __restrict__ ids,
    const f16* __restrict__ w16,
    const float* __restrict__ b_ih,
    const float* __restrict__ b_hh,
    const f16* __restrict__ h16r,
    f16* __restrict__ h16w,
    float* __restrict__ f32w,
    int step)
{
    __shared__ __align__(16) char sB[2][24 * 1024];
    __shared__ __align__(16) char sX[2][16 * 1024];
    __shared__ __align__(16) char sH[2][16 * 1024];
    __shared__ int sXrow[256];

    const int tid = threadIdx.x;
    const int lane = tid & 63, wid = tid >> 6;
    const int wm = wid >> 1, wn = wid & 1;
    const int l15 = lane & 15, lhi = lane >> 4;
    const int bid = blockIdx.x;
    const int rb = (bid & 7) * 4 + (bid >> 6);
    const int cb = (bid >> 3) & 7;
    const int row0 = rb * 256, c0 = cb * 64;

    if (tid < 256) {
        int nn = row0 + tid;
        sXrow[tid] = (nn >> 9) * TT + ids[(size_t)nn * WW + step];
    }
    __syncthreads();

    const f16* bsrc[3]; int bdst[3]; bool bact[3];
    {
        const int slot = lane & 3, lc = lane >> 2;
#pragma unroll
        for (int ii = 0; ii < 3; ++ii) {
            int ch = wid * 3 + ii;
            int g = ch >> 2, cg = ch & 3;
            int col = cg * 16 + lc;
            bact[ii] = HAS_H || (g < 3);
            bsrc[ii] = w16 + ((size_t)(g * 512 + c0 + col) * 512
                              + (size_t)((slot ^ ((col >> 1) & 3)) * 8));
            bdst[ii] = ch * 1024;
        }
    }
    const f16* hsrc[2]; int hdst[2];
    if (HAS_H) {
        const int slot = lane & 3;
#pragma unroll
        for (int ii = 0; ii < 2; ++ii) {
            int ch = wid * 2 + ii;
            int row = ch * 16 + (lane >> 2);
            hsrc[ii] = h16r + ((size_t)(row0 + row) * 512
                               + (size_t)((slot ^ ((lane >> 3) & 3)) * 8));
            hdst[ii] = ch * 1024;
        }
    }
    const int myrow = wid * 32 + (lane >> 1);
    const int bsel = lane & 1;
    const int cA = (2 * bsel) ^ ((myrow >> 1) & 3);
    const float* xsrc = x + (size_t)sXrow[myrow] * DD;
    const float* xp0 = xsrc + cA * 8;
    const float* xp1 = xsrc + (cA ^ 1) * 8;
    const int xw0 = myrow * 64 + (2 * bsel) * 16;

    const int swzo = (lhi ^ ((l15 >> 1) & 3)) * 16;
    const int aA0 = (wm * 64 + l15) * 64 + swzo;
    int colb[2];
#pragma unroll
    for (int nf = 0; nf < 2; ++nf)
        colb[nf] = (wn * 32 + nf * 16 + l15) * 64 + swzo;

    f32x4 accR[4][2], accZ[4][2], accIN[4][2], accHN[4][2];
#pragma unroll
    for (int mf = 0; mf < 4; ++mf)
#pragma unroll
        for (int nf = 0; nf < 2; ++nf) {
            f32x4 z = {0.f, 0.f, 0.f, 0.f};
            accR[mf][nf] = z; accZ[mf][nf] = z; accIN[mf][nf] = z; accHN[mf][nf] = z;
        }

    {
        float4 a0 = *(const float4*)(xp0);
        float4 a1 = *(const float4*)(xp0 + 4);
        float4 a2 = *(const float4*)(xp1);
        float4 a3 = *(const float4*)(xp1 + 4);
#pragma unroll
        for (int ii = 0; ii < 3; ++ii)
            if (bact[ii])
                __builtin_amdgcn_global_load_lds(
                    (const __attribute__((address_space(1))) unsigned*)bsrc[ii],
                    (__attribute__((address_space(3))) unsigned*)(&sB[0][0] + bdst[ii]), 16, 0, 0);
        if (HAS_H) {
#pragma unroll
            for (int ii = 0; ii < 2; ++ii)
                __builtin_amdgcn_global_load_lds(
                    (const __attribute__((address_space(1))) unsigned*)hsrc[ii],
                    (__attribute__((address_space(3))) unsigned*)(&sH[0][0] + hdst[ii]), 16, 0, 0);
        }
        *(f16x8*)(&sX[0][0] + xw0)      = cvt8(a0, a1);
        *(f16x8*)(&sX[0][0] + xw0 + 16) = cvt8(a2, a3);
    }

    int cur = 0;
    for (int ks = 0; ks < 16; ++ks) {
        asm volatile("s_waitcnt vmcnt(0)" ::: "memory");
        __syncthreads();

        float4 a0, a1, a2, a3;
        const int kn = (ks + 1) * 32;
        if (ks < 15) {
            a0 = *(const float4*)(xp0 + kn);
            a1 = *(const float4*)(xp0 + kn + 4);
            a2 = *(const float4*)(xp1 + kn);
            a3 = *(const float4*)(xp1 + kn + 4);
#pragma unroll
            for (int ii = 0; ii < 3; ++ii)
                if (bact[ii])
                    __builtin_amdgcn_global_load_lds(
                        (const __attribute__((address_space(1))) unsigned*)(bsrc[ii] + kn),
                        (__attribute__((address_space(3))) unsigned*)(&sB[cur ^ 1][0] + bdst[ii]), 16, 0, 0);
            if (HAS_H) {
#pragma unroll
                for (int ii = 0; ii < 2; ++ii)
                    __builtin_amdgcn_global_load_lds(
                        (const __attribute__((address_space(1))) unsigned*)(hsrc[ii] + kn),
                        (__attribute__((address_space(3))) unsigned*)(&sH[cur ^ 1][0] + hdst[ii]), 16, 0, 0);
            }
        }

        f16x8 ax[4], ah[4];
#pragma unroll
        for (int mf = 0; mf < 4; ++mf) {
            ax[mf] = *(const f16x8*)(&sX[cur][0] + aA0 + mf * 1024);
            if (HAS_H) ah[mf] = *(const f16x8*)(&sH[cur][0] + aA0 + mf * 1024);
        }

#pragma unroll
        for (int nf = 0; nf < 2; ++nf) {
            const char* bb = &sB[cur][0] + colb[nf];
            f16x8 B0 = *(const f16x8*)(bb + 0 * 4096);
            f16x8 B1 = *(const f16x8*)(bb + 1 * 4096);
            f16x8 B2 = *(const f16x8*)(bb + 2 * 4096);
            f16x8 B3, B4, B5;
            if (HAS_H) {
                B3 = *(const f16x8*)(bb + 3 * 4096);
                B4 = *(const f16x8*)(bb + 4 * 4096);
                B5 = *(const f16x8*)(bb + 5 * 4096);
            }
#pragma unroll
            for (int mf = 0; mf < 4; ++mf) {
                accR[mf][nf]  = MFMA16(ax[mf], B0, accR[mf][nf]);
                accZ[mf][nf]  = MFMA16(ax[mf], B1, accZ[mf][nf]);
                accIN[mf][nf] = MFMA16(ax[mf], B2, accIN[mf][nf]);
                if (HAS_H) {
                    accR[mf][nf]  = MFMA16(ah[mf], B3, accR[mf][nf]);
                    accZ[mf][nf]  = MFMA16(ah[mf], B4, accZ[mf][nf]);
                    accHN[mf][nf] = MFMA16(ah[mf], B5, accHN[mf][nf]);
                }
            }
        }

        if (ks < 15) {
            *(f16x8*)(&sX[cur ^ 1][0] + xw0)      = cvt8(a0, a1);
            *(f16x8*)(&sX[cur ^ 1][0] + xw0 + 16) = cvt8(a2, a3);
        }
        cur ^= 1;
    }

#pragma unroll
    for (int nf = 0; nf < 2; ++nf) {
        int col = c0 + wn * 32 + nf * 16 + l15;
        float bir = b_ih[col],          bhr = b_hh[col];
        float biz = b_ih[DD + col],     bhz = b_hh[DD + col];
        float bin = b_ih[2 * DD + col], bhn = b_hh[2 * DD + col];
#pragma unroll
        for (int mf = 0; mf < 4; ++mf) {
#pragma unroll
            for (int r = 0; r < 4; ++r) {
                int row = row0 + wm * 64 + mf * 16 + lhi * 4 + r;
                size_t off = (size_t)row * DD + col;
                float hold = HAS_H ? (float)h16r[off] : 0.0f;
                float R = fsigm(accR[mf][nf][r] + bir + bhr);
                float Z = fsigm(accZ[mf][nf][r] + biz + bhz);
                float N = ftanh(accIN[mf][nf][r] + bin + R * (accHN[mf][nf][r] + bhn));
                float res = (1.0f - Z) * N + Z * hold;
                if (h16w) h16w[off] = (f16)res;
                if (f32w) f32w[off] = res;
            }
        }
    }
}

// ---------------------------------------------------------------------------
extern "C" void kernel_launch(void* const* d_in, const int* in_sizes, int n_in,
                              void* d_out, int out_size, void* d_ws, size_t ws_size,
                              hipStream_t stream)
{
    const float* x    = (const float*)d_in[0];
    const float* w_ih = (const float*)d_in[1];
    const float* w_hh = (const float*)d_in[2];
    const float* b_ih = (const float*)d_in[3];
    const float* b_hh = (const float*)d_in[4];

    char* ws = (char*)d_ws;
    int*  ids = (int*)(ws + WS_IDS);
    f16*  w16 = (f16*)(ws + WS_W16);
    f16*  P0  = (f16*)(ws + WS_H16);       // ping
    f16*  P1  = (f16*)d_out;               // pong (aliases d_out; last step writes f32)

    select_topk_kernel<<<dim3(NROWS / 4), dim3(256), 0, stream>>>(x, ids);
    convert_w_kernel<<<dim3(1536), dim3(256), 0, stream>>>(w_ih, w_hh, w16);

    if (ws_size >= WS_NEED) {
        // ---- path A: GI precompute + lean h-only steps
        f16* gi = (f16*)(ws + WS_GI);
        gi_gemm_kernel<<<dim3(6144), dim3(256), 0, stream>>>(x, w16, b_ih, gi);
        step0_kernel<<<dim3(2048), dim3(256), 0, stream>>>(ids, gi, b_hh, P0); // h1 -> P0

        for (int s = 1; s < WW; ++s) {
            const f16* hr = (s & 1) ? P0 : P1;
            f16* hw      = (s == WW - 1) ? nullptr : ((s & 1) ? P1 : P0);
            float* fo    = (s == WW - 1) ? (float*)d_out : nullptr;
            gru_step_h_kernel<<<dim3(512), dim3(256), 0, stream>>>(
                ids, w16, b_hh, gi, hr, hw, fo, s);
        }
    } else {
        // ---- path B: proven round-4 both-sides steps
        for (int s = 0; s < WW; ++s) {
            const f16* hr = (s == 0) ? nullptr : ((s & 1) ? P0 : P1);
            f16* hw      = (s == WW - 1) ? nullptr : ((s & 1) ? P1 : P0);
            float* fo    = (s == WW - 1) ? (float*)d_out : nullptr;
            if (s == 0)
                gru_step_full_kernel<false><<<dim3(256), dim3(512), 0, stream>>>(
                    x, ids, w16, b_ih, b_hh, hr, hw, fo, s);
            else
                gru_step_full_kernel<true><<<dim3(256), dim3(512), 0, stream>>>(
                    x, ids, w16, b_ih, b_hh, hr, hw, fo, s);
        }
    }
}